// Round 10
// baseline (334.650 us; speedup 1.0000x reference)
//
#include <hip/hip_runtime.h>
#include <math.h>

// GPTBigCodeAttention: B=2,S=2048,D=2048,H=16,HD=128, MQA (1 shared K/V head)
constexpr int cB  = 2;
constexpr int cS  = 2048;
constexpr int cD  = 2048;
constexpr int cH  = 16;
constexpr int cHD = 128;
constexpr int cNQKV = cH * cHD + 2 * cHD;   // 2304

typedef __attribute__((ext_vector_type(8))) short bf16x8;
typedef __attribute__((ext_vector_type(4))) float f32x4;
typedef __attribute__((ext_vector_type(16))) float f32x16;
typedef __attribute__((ext_vector_type(2))) unsigned uint2v;

__device__ __forceinline__ short f2bf(float f) {
    union { float f; unsigned u; } v; v.f = f;
    unsigned r = (v.u + 0x7FFFu + ((v.u >> 16) & 1u)) >> 16;
    return (short)r;
}

__device__ __forceinline__ unsigned cvt_pk_bf16(float lo, float hi_) {
    unsigned r;
    asm("v_cvt_pk_bf16_f32 %0, %1, %2" : "=v"(r) : "v"(lo), "v"(hi_));
    return r;
}

typedef __attribute__((address_space(3))) void lds_t;
typedef const __attribute__((address_space(1))) void gbl_t;
__device__ __forceinline__ void gld16(const void* g, void* l) {
    __builtin_amdgcn_global_load_lds((gbl_t*)g, (lds_t*)l, 16, 0, 0);
}

// ---------------------------------------------------------------------------
// elementwise fp32 -> bf16 (8 elems/thread)
// ---------------------------------------------------------------------------
__global__ __launch_bounds__(256) void conv_bf16(
    const float* __restrict__ src, short* __restrict__ dst)
{
    size_t i = ((size_t)blockIdx.x * 256 + threadIdx.x) * 8;
    float4 a = *(const float4*)(src + i);
    float4 b = *(const float4*)(src + i + 4);
    bf16x8 o;
    o[0] = f2bf(a.x); o[1] = f2bf(a.y); o[2] = f2bf(a.z); o[3] = f2bf(a.w);
    o[4] = f2bf(b.x); o[5] = f2bf(b.y); o[6] = f2bf(b.z); o[7] = f2bf(b.w);
    *(bf16x8*)(dst + i) = o;
}

// ---------------------------------------------------------------------------
// W fp32 [K][N] -> bf16 [N][K] (transpose), 32x32 LDS tiles
// ---------------------------------------------------------------------------
__global__ __launch_bounds__(256) void transpose_bf16(
    const float* __restrict__ src, short* __restrict__ dst, int K, int N)
{
    __shared__ short t[32][33];
    const int n0 = blockIdx.x * 32, k0 = blockIdx.y * 32;
    const int x = threadIdx.x & 31, y = threadIdx.x >> 5;   // y 0..7
#pragma unroll
    for (int i = 0; i < 4; ++i)
        t[y + 8 * i][x] = f2bf(src[(size_t)(k0 + y + 8 * i) * N + n0 + x]);
    __syncthreads();
#pragma unroll
    for (int i = 0; i < 4; ++i)
        dst[(size_t)(n0 + y + 8 * i) * K + k0 + x] = t[x][y + 8 * i];
}

// ---------------------------------------------------------------------------
// bf16 MFMA GEMM (m97 structure): C[M][N] = A[M][K] @ Bt[N][K]^T + bias
// ---------------------------------------------------------------------------
template<bool BF16_OUT>
__global__ __launch_bounds__(256) void gemm_mfma(
    const short* __restrict__ A, const short* __restrict__ Bt,
    const float* __restrict__ bias, void* __restrict__ Cout,
    int M, int N, int K, float qscale, int qcols)
{
    __shared__ short As[128 * 32];
    __shared__ short Bs[128 * 32];

    const int tid = threadIdx.x;
    const int lane = tid & 63, n16 = lane & 15, quad = lane >> 4;
    const int wave = tid >> 6, wm = wave >> 1, wn = wave & 1;
    const int m0 = blockIdx.y * 128, n0 = blockIdx.x * 128;

    f32x4 acc[4][4];
#pragma unroll
    for (int i = 0; i < 4; ++i)
#pragma unroll
        for (int j = 0; j < 4; ++j) acc[i][j] = 0.0f;

    const int s0 = tid, s1 = tid + 256;
    const short* Ag0 = A  + (size_t)(m0 + (s0 >> 2)) * K + (s0 & 3) * 8;
    const short* Ag1 = A  + (size_t)(m0 + (s1 >> 2)) * K + (s1 & 3) * 8;
    const short* Bg0 = Bt + (size_t)(n0 + (s0 >> 2)) * K + (s0 & 3) * 8;
    const short* Bg1 = Bt + (size_t)(n0 + (s1 >> 2)) * K + (s1 & 3) * 8;

    for (int k0 = 0; k0 < K; k0 += 32) {
        gld16(Ag0 + k0, &As[s0 * 8]);
        gld16(Ag1 + k0, &As[s1 * 8]);
        gld16(Bg0 + k0, &Bs[s0 * 8]);
        gld16(Bg1 + k0, &Bs[s1 * 8]);
        __syncthreads();
        bf16x8 af[4], bfr[4];
#pragma unroll
        for (int mt = 0; mt < 4; ++mt)
            af[mt] = *(const bf16x8*)&As[(wm * 64 + mt * 16 + n16) * 32 + quad * 8];
#pragma unroll
        for (int nt = 0; nt < 4; ++nt)
            bfr[nt] = *(const bf16x8*)&Bs[(wn * 64 + nt * 16 + n16) * 32 + quad * 8];
#pragma unroll
        for (int mt = 0; mt < 4; ++mt)
#pragma unroll
            for (int nt = 0; nt < 4; ++nt)
                acc[mt][nt] = __builtin_amdgcn_mfma_f32_16x16x32_bf16(
                    af[mt], bfr[nt], acc[mt][nt], 0, 0, 0);
        __syncthreads();
    }

#pragma unroll
    for (int nt = 0; nt < 4; ++nt) {
        const int col = n0 + wn * 64 + nt * 16 + n16;
        const float bv = bias[col];
        const float sc = (col < qcols) ? qscale : 1.0f;
#pragma unroll
        for (int mt = 0; mt < 4; ++mt)
#pragma unroll
            for (int r = 0; r < 4; ++r) {
                const int row = m0 + wm * 64 + mt * 16 + quad * 4 + r;
                const float v = (acc[mt][nt][r] + bv) * sc;
                if (BF16_OUT) ((short*)Cout)[(size_t)row * N + col] = f2bf(v);
                else          ((float*)Cout)[(size_t)row * N + col] = v;
            }
    }
}

// ---------------------------------------------------------------------------
// V -> Vt bf16 [b][HD][S] transpose (K is read directly from qkvb)
// ---------------------------------------------------------------------------
__global__ __launch_bounds__(256) void prep_v(
    const short* __restrict__ qkvb, short* __restrict__ Vt)
{
    const int b  = blockIdx.y;
    const int k0 = blockIdx.x * 64;
    const int t  = threadIdx.x;
#pragma unroll
    for (int i = 0; i < 32; ++i) {
        int idx = i * 256 + t;
        int hd = idx >> 6, key = idx & 63;
        Vt[((size_t)b * cHD + hd) * cS + k0 + key] =
            qkvb[((size_t)(b * cS + k0 + key)) * cNQKV + cH * cHD + cHD + hd];
    }
}

// ---------------------------------------------------------------------------
// Pre-permute K and V into MFMA fragment-linear order so attn fragment
// loads are base + lane*16B (coalesced 1KB/instr).
//
// Kf granule (16B): G = (((b*64+g)*8+dblk)*2+hi)*32 + r32
//   holds K[key=g*32+r32][d = dblk*16+hi*8 .. +8]
// Vf granule (16B): G = ((((b*64+kt2)*2+kblk)*4+dtile)*64 + hi*32+q32)
//   holds V[key=kt2*32+kblk*16+hi*8 .. +8][d = dtile*32+q32]  (from Vt)
// ---------------------------------------------------------------------------
__global__ __launch_bounds__(256) void prep_kvf(
    const short* __restrict__ qkvb, const short* __restrict__ Vt,
    short* __restrict__ Kf, short* __restrict__ Vf)
{
    const int gidx = blockIdx.x * 256 + threadIdx.x;   // 0..131071
    if (gidx < 65536) {
        const int idx = gidx;
        const int r32  = idx & 31;
        const int hi   = (idx >> 5) & 1;
        const int dblk = (idx >> 6) & 7;
        const int g    = (idx >> 9) & 63;
        const int b    = idx >> 15;
        const short* src = qkvb + ((size_t)(b * cS) + g * 32 + r32) * cNQKV
                         + cH * cHD + dblk * 16 + hi * 8;
        *(bf16x8*)(Kf + (size_t)idx * 8) = *(const bf16x8*)src;
    } else {
        const int idx = gidx - 65536;
        const int l     = idx & 63;           // hi*32 + q32
        const int dtile = (idx >> 6) & 3;
        const int kblk  = (idx >> 8) & 1;
        const int kt2   = (idx >> 9) & 63;
        const int b     = idx >> 15;
        const int q32 = l & 31, hi = l >> 5;
        const short* src = Vt + ((size_t)(b * cHD) + dtile * 32 + q32) * cS
                         + kt2 * 32 + kblk * 16 + hi * 8;
        *(bf16x8*)(Vf + (size_t)idx * 8) = *(const bf16x8*)src;
    }
}

// ---------------------------------------------------------------------------
// MFMA flash attention (causal, MQA), 32x32 MFMA, swapped QK^T, in-reg P.
// 1-D grid 1024 x 128 threads (2 waves = khalf 0/1). Paired (qt, 31-qt)
// -> every block exactly 33 K-tiles of 64 keys.
//
// r9 counters: MfmaUtil 16% (34k cyc/SIMD) + VALUBusy 36% (75k) = 52%,
// ~48% dual-pipe stall; VALU was 2.2x the MFMA load, dominated by manual
// f2bf packing (~570 VALU/tile). This round cuts the softmax-pack VALU
// with HW ops (T12, proven in learn_hip m214v22):
//  - v_cvt_pk_bf16_f32 (1 instr per f32-pair, was ~10)
//  - permlane32_swap: one swap yields BOTH halves' fragment words
//    (replaces 4 shfl_xor + 16 cndmask per tile)
//  - Q pre-scaled by log2(e)/sqrt(HD) in GEMM1 -> p = exp2f(s), bare
//    v_exp_f32 (softmax is change-of-base invariant; mask -1e30 -> 0)
//
// VGPR=232 zero-spill config (WG=128, launch_bounds(128)); WRITE_SIZE
// 16.4MB = output exactly. XCD remap: same-b blocks share an XCD pair.
// K/V from fragment-linear Kf/Vf (coalesced, L2-resident, FETCH 12.4MB).
// Zero main-loop barriers/LDS. K regs reload after QK^T; V after PV.
// ---------------------------------------------------------------------------
__global__ __launch_bounds__(128) void attn_mfma(
    const short* __restrict__ qkvb, const short* __restrict__ Kf,
    const short* __restrict__ Vf, short* __restrict__ out)
{
    const int tid  = threadIdx.x;
    const int lane = tid & 63;
    const int q32  = lane & 31;         // q-col (B/C) or key-row (A) selector
    const int hi   = lane >> 5;         // k-chunk half selector
    const int khalf = tid >> 6;         // wave 0/1: keys khalf*32..+32 of tile

    // XCD-aware decode: xcd = id&7 (dispatch round-robin), b from xcd.
    const int lid = (int)blockIdx.x;    // 0..1023
    const int xcd = lid & 7;
    const int j   = lid >> 3;           // 0..127
    const int b   = xcd >> 2;
    const int h     = (xcd & 3) * 4 + (j >> 5);
    const int qhalf = (j >> 4) & 1;
    const int qtx   = j & 15;

    __shared__ __align__(16) float Obuf[32][128];   // 16 KB khalf-combine
    __shared__ float Lbuf[32];
    __shared__ float Linv[32];

#pragma unroll 1
    for (int seg = 0; seg < 2; ++seg) {
        const int qt = seg ? qtx : 31 - qtx;     // big first
        const int qb = qt * 64;
        const int qg = qb + qhalf * 32 + q32;    // this lane's q (as B/C col)
        const int nkt = qt + 1;

        // Q fragments (B operand): lane holds Q[q=qg][d = dblk*16 + hi*8 + j]
        bf16x8 qf[8];
        {
            const short* qbase = qkvb + ((size_t)(b * cS) + qg) * cNQKV
                               + h * cHD + hi * 8;
#pragma unroll
            for (int dblk = 0; dblk < 8; ++dblk)
                qf[dblk] = *(const bf16x8*)(qbase + dblk * 16);
        }

        f32x16 oc[4];
#pragma unroll
        for (int i = 0; i < 4; ++i) oc[i] = 0.0f;
        float lp = 0.0f;

        // fragment-linear bases for kt=0 (advance 8192 shorts per kt)
        const short* kfp = Kf + ((size_t)(b * 64) + khalf) * 4096
                         + hi * 256 + q32 * 8;
        const short* vfp = Vf + ((size_t)(b * 64) + khalf) * 4096 + lane * 8;

        bf16x8 kfc[8], vfc[8];
#pragma unroll
        for (int dblk = 0; dblk < 8; ++dblk)       // kt=0 K fragments
            kfc[dblk] = *(const bf16x8*)(kfp + dblk * 512);
#pragma unroll
        for (int u = 0; u < 8; ++u)                // kt=0 V fragments
            vfc[u] = *(const bf16x8*)(vfp + u * 512);

#pragma unroll 1
        for (int kt = 0; kt < nkt; ++kt) {
            const int k0 = kt * 64;

            // ---- S^T = K @ Q^T for this wave's khalf 32-key slab ----
            f32x16 sc = 0.0f;
            __builtin_amdgcn_s_setprio(1);
#pragma unroll
            for (int dblk = 0; dblk < 8; ++dblk)
                sc = __builtin_amdgcn_mfma_f32_32x32x16_bf16(
                    kfc[dblk], qf[dblk], sc, 0, 0, 0);
            __builtin_amdgcn_s_setprio(0);

            // ---- reload K frags for kt+1 into just-freed regs ----
            if (kt + 1 < nkt) {
                const short* kn = kfp + (size_t)(kt + 1) * 8192;
#pragma unroll
                for (int dblk = 0; dblk < 8; ++dblk)
                    kfc[dblk] = *(const bf16x8*)(kn + dblk * 512);
            }

            // ---- mask (diagonal only) + exp2; value layout:
            // sc[r] = S[k = k0+khalf*32+(r&3)+8*(r>>2)+4*hi][q = qg] ----
            // S already in log2 domain (Q pre-scaled by log2e/sqrt(HD)).
            const bool diag = (kt == nkt - 1);
            float e[16];
#pragma unroll
            for (int r = 0; r < 16; ++r) {
                float s = sc[r];
                if (diag) {
                    int kgl = k0 + khalf * 32 + (r & 3) + 8 * (r >> 2) + 4 * hi;
                    if (kgl > qg) s = -1e30f;
                }
                float p = exp2f(s);      // masked: exp2(-1e30)=0
                lp += p;
                e[r] = p;
            }

            // ---- P -> A-frags in-register (cvt_pk + permlane32_swap) ----
            // target: pa[kblk] elem j = P[qg][k = khalf*32 + kblk*16 + hi*8 + j]
            // e[rb+i] covers k_e = 16kblk + 8*(i>>2) + 4*hi + (i&3).
            // One permlane32_swap(A,B) yields u_low for BOTH halves in .x
            // and u_high for BOTH halves in .y (lane i<->i+32 exchange).
            bf16x8 pa[2];
#pragma unroll
            for (int kblk = 0; kblk < 2; ++kblk) {
                const int rb = 8 * kblk;
                unsigned a0 = cvt_pk_bf16(e[rb + 0], e[rb + 1]);
                unsigned a1 = cvt_pk_bf16(e[rb + 2], e[rb + 3]);
                unsigned b0 = cvt_pk_bf16(e[rb + 4], e[rb + 5]);
                unsigned b1 = cvt_pk_bf16(e[rb + 6], e[rb + 7]);
                uint2v r0 = __builtin_amdgcn_permlane32_swap(a0, b0, 0, 0);
                uint2v r1 = __builtin_amdgcn_permlane32_swap(a1, b1, 0, 0);
                union { unsigned u[4]; bf16x8 v; } uu;
                uu.u[0] = r0.x; uu.u[1] = r1.x;
                uu.u[2] = r0.y; uu.u[3] = r1.y;
                pa[kblk] = uu.v;
            }

            // ---- O_partial += P @ V (this wave's khalf keys only) ----
            // vfc[kblk*4+dtile]: V[k=khalf*32+kblk*16+hi*8+j][d=dtile*32+q32]
            __builtin_amdgcn_s_setprio(1);
#pragma unroll
            for (int dtile = 0; dtile < 4; ++dtile) {
                oc[dtile] = __builtin_amdgcn_mfma_f32_32x32x16_bf16(
                    pa[0], vfc[dtile], oc[dtile], 0, 0, 0);
                oc[dtile] = __builtin_amdgcn_mfma_f32_32x32x16_bf16(
                    pa[1], vfc[4 + dtile], oc[dtile], 0, 0, 0);
            }
            __builtin_amdgcn_s_setprio(0);

            // ---- reload V frags for kt+1 into just-freed regs ----
            if (kt + 1 < nkt) {
                const short* vn = vfp + (size_t)(kt + 1) * 8192;
#pragma unroll
                for (int u = 0; u < 8; ++u)
                    vfc[u] = *(const bf16x8*)(vn + u * 512);
            }
        }

        // ---- combine khalf partials, then divide + write ----
        lp += __shfl_xor(lp, 32);           // full sum over wave's 32 keys
        __syncthreads();                    // Obuf free (prev seg consumed)
        if (khalf == 1) {
#pragma unroll
            for (int dtile = 0; dtile < 4; ++dtile)
#pragma unroll
                for (int r = 0; r < 16; ++r) {
                    const int q = (r & 3) + 8 * (r >> 2) + 4 * hi;
                    Obuf[q][dtile * 32 + q32] = oc[dtile][r];
                }
            if (hi == 0) Lbuf[q32] = lp;
        }
        __syncthreads();
        if (khalf == 0) {
#pragma unroll
            for (int dtile = 0; dtile < 4; ++dtile)
#pragma unroll
                for (int r = 0; r < 16; ++r) {
                    const int q = (r & 3) + 8 * (r >> 2) + 4 * hi;
                    oc[dtile][r] += Obuf[q][dtile * 32 + q32];
                }
            lp += Lbuf[q32];
            if (hi == 0) Linv[q32] = 1.0f / lp;
        }
        __syncthreads();
        if (khalf == 0) {
            f32x4 invv[4];
#pragma unroll
            for (int g = 0; g < 4; ++g)
                invv[g] = *(const f32x4*)&Linv[g * 8 + hi * 4];
            short* obase = out + ((size_t)(b * cS) + qb + qhalf * 32) * cD + h * cHD;
#pragma unroll
            for (int dtile = 0; dtile < 4; ++dtile)
#pragma unroll
                for (int r = 0; r < 16; ++r) {
                    const int q = (r & 3) + 8 * (r >> 2) + 4 * hi;
                    obase[(size_t)q * cD + dtile * 32 + q32] =
                        f2bf(oc[dtile][r] * invv[r >> 2][r & 3]);
                }
        }
    }
}

// ---------------------------------------------------------------------------
extern "C" void kernel_launch(void* const* d_in, const int* in_sizes, int n_in,
                              void* d_out, int out_size, void* d_ws, size_t ws_size,
                              hipStream_t stream)
{
    const float* hidden = (const float*)d_in[0];
    const float* W_attn = (const float*)d_in[1];
    const float* b_attn = (const float*)d_in[2];
    const float* W_proj = (const float*)d_in[3];
    const float* b_proj = (const float*)d_in[4];
    float* out = (float*)d_out;

    const int M = cB * cS;  // 4096
    short* qkvb = (short*)d_ws;
    short* Ah   = qkvb + (size_t)M * cNQKV;
    short* Wb   = Ah   + (size_t)M * cD;
    short* Wpb  = Wb   + (size_t)cNQKV * cD;
    short* Vt   = Wpb  + (size_t)cD * cD;
    short* Kf   = Vt   + (size_t)cB * cHD * cS;
    short* Vf   = Kf   + (size_t)cB * cS * cHD;
    short* attno = Ah;  // alias: Ah dead after GEMM1

    // log2(e) / sqrt(128): Q pre-scaled so attn softmax uses exp2 directly
    const float scale = 0.12751743f;

    conv_bf16<<<(size_t)M * cD / 2048, 256, 0, stream>>>(hidden, Ah);
    transpose_bf16<<<dim3(cNQKV / 32, cD / 32), 256, 0, stream>>>(W_attn, Wb, cD, cNQKV);
    transpose_bf16<<<dim3(cD / 32, cD / 32), 256, 0, stream>>>(W_proj, Wpb, cD, cD);

    gemm_mfma<true><<<dim3(cNQKV / 128, M / 128), 256, 0, stream>>>(
        Ah, Wb, b_attn, qkvb, M, cNQKV, cD, scale, cH * cHD);

    prep_v<<<dim3(cS / 64, cB), 256, 0, stream>>>(qkvb, Vt);
    prep_kvf<<<512, 256, 0, stream>>>(qkvb, Vt, Kf, Vf);

    attn_mfma<<<1024, 128, 0, stream>>>(qkvb, Kf, Vf, attno);

    gemm_mfma<false><<<dim3(cD / 128, M / 128), 256, 0, stream>>>(
        attno, Wpb, b_proj, out, M, cD, cD, 1.0f, 0);
}

// Round 11
// 328.467 us; speedup vs baseline: 1.0188x; 1.0188x over previous
//
#include <hip/hip_runtime.h>
#include <math.h>

// GPTBigCodeAttention: B=2,S=2048,D=2048,H=16,HD=128, MQA (1 shared K/V head)
constexpr int cB  = 2;
constexpr int cS  = 2048;
constexpr int cD  = 2048;
constexpr int cH  = 16;
constexpr int cHD = 128;
constexpr int cNQKV = cH * cHD + 2 * cHD;   // 2304

typedef __attribute__((ext_vector_type(8))) short bf16x8;
typedef __attribute__((ext_vector_type(4))) float f32x4;
typedef __attribute__((ext_vector_type(16))) float f32x16;
typedef __attribute__((ext_vector_type(2))) unsigned uint2v;

__device__ __forceinline__ short f2bf(float f) {
    union { float f; unsigned u; } v; v.f = f;
    unsigned r = (v.u + 0x7FFFu + ((v.u >> 16) & 1u)) >> 16;
    return (short)r;
}

__device__ __forceinline__ unsigned pk_bf16(float lo, float hi_) {
    return (unsigned)(unsigned short)f2bf(lo)
         | ((unsigned)(unsigned short)f2bf(hi_) << 16);
}

typedef __attribute__((address_space(3))) void lds_t;
typedef const __attribute__((address_space(1))) void gbl_t;
__device__ __forceinline__ void gld16(const void* g, void* l) {
    __builtin_amdgcn_global_load_lds((gbl_t*)g, (lds_t*)l, 16, 0, 0);
}

// ---------------------------------------------------------------------------
// elementwise fp32 -> bf16 (8 elems/thread)
// ---------------------------------------------------------------------------
__global__ __launch_bounds__(256) void conv_bf16(
    const float* __restrict__ src, short* __restrict__ dst)
{
    size_t i = ((size_t)blockIdx.x * 256 + threadIdx.x) * 8;
    float4 a = *(const float4*)(src + i);
    float4 b = *(const float4*)(src + i + 4);
    bf16x8 o;
    o[0] = f2bf(a.x); o[1] = f2bf(a.y); o[2] = f2bf(a.z); o[3] = f2bf(a.w);
    o[4] = f2bf(b.x); o[5] = f2bf(b.y); o[6] = f2bf(b.z); o[7] = f2bf(b.w);
    *(bf16x8*)(dst + i) = o;
}

// ---------------------------------------------------------------------------
// W fp32 [K][N] -> bf16 [N][K] (transpose), 32x32 LDS tiles
// ---------------------------------------------------------------------------
__global__ __launch_bounds__(256) void transpose_bf16(
    const float* __restrict__ src, short* __restrict__ dst, int K, int N)
{
    __shared__ short t[32][33];
    const int n0 = blockIdx.x * 32, k0 = blockIdx.y * 32;
    const int x = threadIdx.x & 31, y = threadIdx.x >> 5;   // y 0..7
#pragma unroll
    for (int i = 0; i < 4; ++i)
        t[y + 8 * i][x] = f2bf(src[(size_t)(k0 + y + 8 * i) * N + n0 + x]);
    __syncthreads();
#pragma unroll
    for (int i = 0; i < 4; ++i)
        dst[(size_t)(n0 + y + 8 * i) * K + k0 + x] = t[x][y + 8 * i];
}

// ---------------------------------------------------------------------------
// bf16 MFMA GEMM: C[M][N] = A[M][K] @ Bt[N][K]^T + bias.
// r11: double-buffered LDS + one barrier per K-step (T3 minimum 2-phase:
// issue NEXT tile's global_load_lds right after the barrier, compute the
// CURRENT buffer, barrier drains vmcnt for the prefetch). Same pattern
// gave attn +29% in r1. Was: stage-current + 2 barriers/K-step (staging
// latency fully exposed).
// ---------------------------------------------------------------------------
template<bool BF16_OUT>
__global__ __launch_bounds__(256) void gemm_mfma(
    const short* __restrict__ A, const short* __restrict__ Bt,
    const float* __restrict__ bias, void* __restrict__ Cout,
    int M, int N, int K, float qscale, int qcols)
{
    __shared__ short As[2][128 * 32];
    __shared__ short Bs[2][128 * 32];

    const int tid = threadIdx.x;
    const int lane = tid & 63, n16 = lane & 15, quad = lane >> 4;
    const int wave = tid >> 6, wm = wave >> 1, wn = wave & 1;
    const int m0 = blockIdx.y * 128, n0 = blockIdx.x * 128;

    f32x4 acc[4][4];
#pragma unroll
    for (int i = 0; i < 4; ++i)
#pragma unroll
        for (int j = 0; j < 4; ++j) acc[i][j] = 0.0f;

    const int s0 = tid, s1 = tid + 256;
    const short* Ag0 = A  + (size_t)(m0 + (s0 >> 2)) * K + (s0 & 3) * 8;
    const short* Ag1 = A  + (size_t)(m0 + (s1 >> 2)) * K + (s1 & 3) * 8;
    const short* Bg0 = Bt + (size_t)(n0 + (s0 >> 2)) * K + (s0 & 3) * 8;
    const short* Bg1 = Bt + (size_t)(n0 + (s1 >> 2)) * K + (s1 & 3) * 8;

    auto stage = [&](int buf, int k0) {
        gld16(Ag0 + k0, &As[buf][s0 * 8]);
        gld16(Ag1 + k0, &As[buf][s1 * 8]);
        gld16(Bg0 + k0, &Bs[buf][s0 * 8]);
        gld16(Bg1 + k0, &Bs[buf][s1 * 8]);
    };

    int cur = 0;
    stage(0, 0);                        // prologue prefetch

    for (int k0 = 0; k0 < K; k0 += 32) {
        __syncthreads();                // buf[cur] staged (vmcnt drained) +
                                        // all waves done reading buf[cur^1]
        if (k0 + 32 < K) stage(cur ^ 1, k0 + 32);   // prefetch next tile

        bf16x8 af[4], bfr[4];
#pragma unroll
        for (int mt = 0; mt < 4; ++mt)
            af[mt] = *(const bf16x8*)&As[cur][(wm * 64 + mt * 16 + n16) * 32 + quad * 8];
#pragma unroll
        for (int nt = 0; nt < 4; ++nt)
            bfr[nt] = *(const bf16x8*)&Bs[cur][(wn * 64 + nt * 16 + n16) * 32 + quad * 8];
#pragma unroll
        for (int mt = 0; mt < 4; ++mt)
#pragma unroll
            for (int nt = 0; nt < 4; ++nt)
                acc[mt][nt] = __builtin_amdgcn_mfma_f32_16x16x32_bf16(
                    af[mt], bfr[nt], acc[mt][nt], 0, 0, 0);
        cur ^= 1;
    }

#pragma unroll
    for (int nt = 0; nt < 4; ++nt) {
        const int col = n0 + wn * 64 + nt * 16 + n16;
        const float bv = bias[col];
        const float sc = (col < qcols) ? qscale : 1.0f;
#pragma unroll
        for (int mt = 0; mt < 4; ++mt)
#pragma unroll
            for (int r = 0; r < 4; ++r) {
                const int row = m0 + wm * 64 + mt * 16 + quad * 4 + r;
                const float v = (acc[mt][nt][r] + bv) * sc;
                if (BF16_OUT) ((short*)Cout)[(size_t)row * N + col] = f2bf(v);
                else          ((float*)Cout)[(size_t)row * N + col] = v;
            }
    }
}

// ---------------------------------------------------------------------------
// V -> Vt bf16 [b][HD][S] transpose (K is read directly from qkvb)
// ---------------------------------------------------------------------------
__global__ __launch_bounds__(256) void prep_v(
    const short* __restrict__ qkvb, short* __restrict__ Vt)
{
    const int b  = blockIdx.y;
    const int k0 = blockIdx.x * 64;
    const int t  = threadIdx.x;
#pragma unroll
    for (int i = 0; i < 32; ++i) {
        int idx = i * 256 + t;
        int hd = idx >> 6, key = idx & 63;
        Vt[((size_t)b * cHD + hd) * cS + k0 + key] =
            qkvb[((size_t)(b * cS + k0 + key)) * cNQKV + cH * cHD + cHD + hd];
    }
}

// ---------------------------------------------------------------------------
// Pre-permute K and V into MFMA fragment-linear order so attn fragment
// loads are base + lane*16B (coalesced 1KB/instr).
//
// Kf granule (16B): G = (((b*64+g)*8+dblk)*2+hi)*32 + r32
//   holds K[key=g*32+r32][d = dblk*16+hi*8 .. +8]
// Vf granule (16B): G = ((((b*64+kt2)*2+kblk)*4+dtile)*64 + hi*32+q32)
//   holds V[key=kt2*32+kblk*16+hi*8 .. +8][d = dtile*32+q32]  (from Vt)
// ---------------------------------------------------------------------------
__global__ __launch_bounds__(256) void prep_kvf(
    const short* __restrict__ qkvb, const short* __restrict__ Vt,
    short* __restrict__ Kf, short* __restrict__ Vf)
{
    const int gidx = blockIdx.x * 256 + threadIdx.x;   // 0..131071
    if (gidx < 65536) {
        const int idx = gidx;
        const int r32  = idx & 31;
        const int hi   = (idx >> 5) & 1;
        const int dblk = (idx >> 6) & 7;
        const int g    = (idx >> 9) & 63;
        const int b    = idx >> 15;
        const short* src = qkvb + ((size_t)(b * cS) + g * 32 + r32) * cNQKV
                         + cH * cHD + dblk * 16 + hi * 8;
        *(bf16x8*)(Kf + (size_t)idx * 8) = *(const bf16x8*)src;
    } else {
        const int idx = gidx - 65536;
        const int l     = idx & 63;           // hi*32 + q32
        const int dtile = (idx >> 6) & 3;
        const int kblk  = (idx >> 8) & 1;
        const int kt2   = (idx >> 9) & 63;
        const int b     = idx >> 15;
        const int q32 = l & 31, hi = l >> 5;
        const short* src = Vt + ((size_t)(b * cHD) + dtile * 32 + q32) * cS
                         + kt2 * 32 + kblk * 16 + hi * 8;
        *(bf16x8*)(Vf + (size_t)idx * 8) = *(const bf16x8*)src;
    }
}

// ---------------------------------------------------------------------------
// MFMA flash attention (causal, MQA), 32x32 MFMA, swapped QK^T, in-reg P.
// 1-D grid 1024 x 128 threads (2 waves = khalf 0/1). Paired (qt, 31-qt)
// -> every block exactly 33 K-tiles of 64 keys.
//
// r10 lesson (matches learn_hip m240): inline-asm v_cvt_pk_bf16_f32
// REGRESSED (-4us, VALUBusy up) -- reverted to scalar-cast packing.
// Kept: permlane32_swap (one swap yields both halves' fragment words)
// and exp2-domain softmax (Q pre-scaled by log2e/sqrt(HD) in GEMM1).
//
// VGPR~232 zero-spill config (WG=128, launch_bounds(128)); WRITE_SIZE
// 16.4MB = output exactly. XCD remap: same-b blocks share an XCD pair.
// K/V from fragment-linear Kf/Vf (coalesced, L2-resident, FETCH 12.4MB).
// Zero main-loop barriers/LDS. K regs reload after QK^T; V after PV.
// Plateau note: MfmaUtil 16% + VALUBusy 36% at 2 waves/SIMD = latency
// bound; next lever would be a register diet to 3 waves/SIMD.
// ---------------------------------------------------------------------------
__global__ __launch_bounds__(128) void attn_mfma(
    const short* __restrict__ qkvb, const short* __restrict__ Kf,
    const short* __restrict__ Vf, short* __restrict__ out)
{
    const int tid  = threadIdx.x;
    const int lane = tid & 63;
    const int q32  = lane & 31;         // q-col (B/C) or key-row (A) selector
    const int hi   = lane >> 5;         // k-chunk half selector
    const int khalf = tid >> 6;         // wave 0/1: keys khalf*32..+32 of tile

    // XCD-aware decode: xcd = id&7 (dispatch round-robin), b from xcd.
    const int lid = (int)blockIdx.x;    // 0..1023
    const int xcd = lid & 7;
    const int j   = lid >> 3;           // 0..127
    const int b   = xcd >> 2;
    const int h     = (xcd & 3) * 4 + (j >> 5);
    const int qhalf = (j >> 4) & 1;
    const int qtx   = j & 15;

    __shared__ __align__(16) float Obuf[32][128];   // 16 KB khalf-combine
    __shared__ float Lbuf[32];
    __shared__ float Linv[32];

#pragma unroll 1
    for (int seg = 0; seg < 2; ++seg) {
        const int qt = seg ? qtx : 31 - qtx;     // big first
        const int qb = qt * 64;
        const int qg = qb + qhalf * 32 + q32;    // this lane's q (as B/C col)
        const int nkt = qt + 1;

        // Q fragments (B operand): lane holds Q[q=qg][d = dblk*16 + hi*8 + j]
        bf16x8 qf[8];
        {
            const short* qbase = qkvb + ((size_t)(b * cS) + qg) * cNQKV
                               + h * cHD + hi * 8;
#pragma unroll
            for (int dblk = 0; dblk < 8; ++dblk)
                qf[dblk] = *(const bf16x8*)(qbase + dblk * 16);
        }

        f32x16 oc[4];
#pragma unroll
        for (int i = 0; i < 4; ++i) oc[i] = 0.0f;
        float lp = 0.0f;

        // fragment-linear bases for kt=0 (advance 8192 shorts per kt)
        const short* kfp = Kf + ((size_t)(b * 64) + khalf) * 4096
                         + hi * 256 + q32 * 8;
        const short* vfp = Vf + ((size_t)(b * 64) + khalf) * 4096 + lane * 8;

        bf16x8 kfc[8], vfc[8];
#pragma unroll
        for (int dblk = 0; dblk < 8; ++dblk)       // kt=0 K fragments
            kfc[dblk] = *(const bf16x8*)(kfp + dblk * 512);
#pragma unroll
        for (int u = 0; u < 8; ++u)                // kt=0 V fragments
            vfc[u] = *(const bf16x8*)(vfp + u * 512);

#pragma unroll 1
        for (int kt = 0; kt < nkt; ++kt) {
            const int k0 = kt * 64;

            // ---- S^T = K @ Q^T for this wave's khalf 32-key slab ----
            f32x16 sc = 0.0f;
            __builtin_amdgcn_s_setprio(1);
#pragma unroll
            for (int dblk = 0; dblk < 8; ++dblk)
                sc = __builtin_amdgcn_mfma_f32_32x32x16_bf16(
                    kfc[dblk], qf[dblk], sc, 0, 0, 0);
            __builtin_amdgcn_s_setprio(0);

            // ---- reload K frags for kt+1 into just-freed regs ----
            if (kt + 1 < nkt) {
                const short* kn = kfp + (size_t)(kt + 1) * 8192;
#pragma unroll
                for (int dblk = 0; dblk < 8; ++dblk)
                    kfc[dblk] = *(const bf16x8*)(kn + dblk * 512);
            }

            // ---- mask (diagonal only) + exp2; value layout:
            // sc[r] = S[k = k0+khalf*32+(r&3)+8*(r>>2)+4*hi][q = qg] ----
            // S already in log2 domain (Q pre-scaled by log2e/sqrt(HD)).
            const bool diag = (kt == nkt - 1);
            float e[16];
#pragma unroll
            for (int r = 0; r < 16; ++r) {
                float s = sc[r];
                if (diag) {
                    int kgl = k0 + khalf * 32 + (r & 3) + 8 * (r >> 2) + 4 * hi;
                    if (kgl > qg) s = -1e30f;
                }
                float p = exp2f(s);      // masked: exp2(-1e30)=0
                lp += p;
                e[r] = p;
            }

            // ---- P -> A-frags in-register (scalar pack + permlane32_swap) --
            // target: pa[kblk] elem j = P[qg][k = khalf*32 + kblk*16 + hi*8 + j]
            // e[rb+i] covers k_e = 16kblk + 8*(i>>2) + 4*hi + (i&3).
            // One permlane32_swap(A,B) yields u_low for BOTH halves in .x
            // and u_high for BOTH halves in .y (lane i<->i+32 exchange).
            bf16x8 pa[2];
#pragma unroll
            for (int kblk = 0; kblk < 2; ++kblk) {
                const int rb = 8 * kblk;
                unsigned a0 = pk_bf16(e[rb + 0], e[rb + 1]);
                unsigned a1 = pk_bf16(e[rb + 2], e[rb + 3]);
                unsigned b0 = pk_bf16(e[rb + 4], e[rb + 5]);
                unsigned b1 = pk_bf16(e[rb + 6], e[rb + 7]);
                uint2v r0 = __builtin_amdgcn_permlane32_swap(a0, b0, 0, 0);
                uint2v r1 = __builtin_amdgcn_permlane32_swap(a1, b1, 0, 0);
                union { unsigned u[4]; bf16x8 v; } uu;
                uu.u[0] = r0.x; uu.u[1] = r1.x;
                uu.u[2] = r0.y; uu.u[3] = r1.y;
                pa[kblk] = uu.v;
            }

            // ---- O_partial += P @ V (this wave's khalf keys only) ----
            // vfc[kblk*4+dtile]: V[k=khalf*32+kblk*16+hi*8+j][d=dtile*32+q32]
            __builtin_amdgcn_s_setprio(1);
#pragma unroll
            for (int dtile = 0; dtile < 4; ++dtile) {
                oc[dtile] = __builtin_amdgcn_mfma_f32_32x32x16_bf16(
                    pa[0], vfc[dtile], oc[dtile], 0, 0, 0);
                oc[dtile] = __builtin_amdgcn_mfma_f32_32x32x16_bf16(
                    pa[1], vfc[4 + dtile], oc[dtile], 0, 0, 0);
            }
            __builtin_amdgcn_s_setprio(0);

            // ---- reload V frags for kt+1 into just-freed regs ----
            if (kt + 1 < nkt) {
                const short* vn = vfp + (size_t)(kt + 1) * 8192;
#pragma unroll
                for (int u = 0; u < 8; ++u)
                    vfc[u] = *(const bf16x8*)(vn + u * 512);
            }
        }

        // ---- combine khalf partials, then divide + write ----
        lp += __shfl_xor(lp, 32);           // full sum over wave's 32 keys
        __syncthreads();                    // Obuf free (prev seg consumed)
        if (khalf == 1) {
#pragma unroll
            for (int dtile = 0; dtile < 4; ++dtile)
#pragma unroll
                for (int r = 0; r < 16; ++r) {
                    const int q = (r & 3) + 8 * (r >> 2) + 4 * hi;
                    Obuf[q][dtile * 32 + q32] = oc[dtile][r];
                }
            if (hi == 0) Lbuf[q32] = lp;
        }
        __syncthreads();
        if (khalf == 0) {
#pragma unroll
            for (int dtile = 0; dtile < 4; ++dtile)
#pragma unroll
                for (int r = 0; r < 16; ++r) {
                    const int q = (r & 3) + 8 * (r >> 2) + 4 * hi;
                    oc[dtile][r] += Obuf[q][dtile * 32 + q32];
                }
            lp += Lbuf[q32];
            if (hi == 0) Linv[q32] = 1.0f / lp;
        }
        __syncthreads();
        if (khalf == 0) {
            f32x4 invv[4];
#pragma unroll
            for (int g = 0; g < 4; ++g)
                invv[g] = *(const f32x4*)&Linv[g * 8 + hi * 4];
            short* obase = out + ((size_t)(b * cS) + qb + qhalf * 32) * cD + h * cHD;
#pragma unroll
            for (int dtile = 0; dtile < 4; ++dtile)
#pragma unroll
                for (int r = 0; r < 16; ++r) {
                    const int q = (r & 3) + 8 * (r >> 2) + 4 * hi;
                    obase[(size_t)q * cD + dtile * 32 + q32] =
                        f2bf(oc[dtile][r] * invv[r >> 2][r & 3]);
                }
        }
    }
}

// ---------------------------------------------------------------------------
extern "C" void kernel_launch(void* const* d_in, const int* in_sizes, int n_in,
                              void* d_out, int out_size, void* d_ws, size_t ws_size,
                              hipStream_t stream)
{
    const float* hidden = (const float*)d_in[0];
    const float* W_attn = (const float*)d_in[1];
    const float* b_attn = (const float*)d_in[2];
    const float* W_proj = (const float*)d_in[3];
    const float* b_proj = (const float*)d_in[4];
    float* out = (float*)d_out;

    const int M = cB * cS;  // 4096
    short* qkvb = (short*)d_ws;
    short* Ah   = qkvb + (size_t)M * cNQKV;
    short* Wb   = Ah   + (size_t)M * cD;
    short* Wpb  = Wb   + (size_t)cNQKV * cD;
    short* Vt   = Wpb  + (size_t)cD * cD;
    short* Kf   = Vt   + (size_t)cB * cHD * cS;
    short* Vf   = Kf   + (size_t)cB * cS * cHD;
    short* attno = Ah;  // alias: Ah dead after GEMM1

    // log2(e) / sqrt(128): Q pre-scaled so attn softmax uses exp2 directly
    const float scale = 0.12751743f;

    conv_bf16<<<(size_t)M * cD / 2048, 256, 0, stream>>>(hidden, Ah);
    transpose_bf16<<<dim3(cNQKV / 32, cD / 32), 256, 0, stream>>>(W_attn, Wb, cD, cNQKV);
    transpose_bf16<<<dim3(cD / 32, cD / 32), 256, 0, stream>>>(W_proj, Wpb, cD, cD);

    gemm_mfma<true><<<dim3(cNQKV / 128, M / 128), 256, 0, stream>>>(
        Ah, Wb, b_attn, qkvb, M, cNQKV, cD, scale, cH * cHD);

    prep_v<<<dim3(cS / 64, cB), 256, 0, stream>>>(qkvb, Vt);
    prep_kvf<<<512, 256, 0, stream>>>(qkvb, Vt, Kf, Vf);

    attn_mfma<<<1024, 128, 0, stream>>>(qkvb, Kf, Vf, attno);

    gemm_mfma<false><<<dim3(cD / 128, M / 128), 256, 0, stream>>>(
        attno, Wpb, b_proj, out, M, cD, cD, 1.0f, 0);
}